// Round 4
// baseline (37.120 us; speedup 1.0000x reference)
//
#include <hip/hip_runtime.h>
#include <hip/hip_bf16.h>

using f32x4  = __attribute__((ext_vector_type(4))) float;
using bf16x8 = __attribute__((ext_vector_type(8))) short;

constexpr int   G_NUM  = 256;
constexpr int   NAUG   = 256;
constexpr int   NORIG  = 512;
constexpr int   DIM    = 128;
constexpr float INV_T  = 10.0f;
constexpr int   NBLK   = 512;

// round-to-nearest-even f32 -> bf16 bits
__device__ __forceinline__ short f32_to_bf16_bits(float x) {
    unsigned u = __float_as_uint(x);
    u += 0x7fffu + ((u >> 16) & 1u);
    return (short)(u >> 16);
}

// 512 blocks = 2 per graph (each owns 128 student rows). 512 threads = 8 waves.
// Deferred normalization (raw bf16 into MFMA, rsqrt scales on f32 scores).
// All global loads issued up-front; teacher tile processed in two 128-row
// halves so MFMA on half 1 overlaps the half-2 LDS writes / load tail.
// Fused final reduction: fence + counter, last block reduces deterministically.
__global__ __launch_bounds__(512, 4) void nlcl_main(
    const float* __restrict__ student,
    const float* __restrict__ teacher,
    const int*   __restrict__ kept,
    float*       __restrict__ block_sums,
    unsigned*    __restrict__ counter,
    float*       __restrict__ out)
{
    __shared__ short t_lds[NAUG * DIM];   // [256 rows][128 bf16], XOR-swizzled, 64KB
    __shared__ float rt_lds[NAUG];        // rsqrt(sumsq) per teacher tile row
    __shared__ float rs_lds[128];         // rsqrt(sumsq)*10 per student row
    __shared__ float red[8];
    __shared__ int   is_last;

    const int bid = blockIdx.x;
    // XCD-bijective swizzle (512 = 8 XCDs x 64): logical pairs (2g,2g+1) same XCD
    const int logical = (bid & 7) * 64 + (bid >> 3);
    const int g    = logical >> 1;
    const int half = logical & 1;

    const int tid  = threadIdx.x;
    const int lane = tid & 63;
    const int wave = tid >> 6;        // 0..7
    const int rbase = half * 128;     // this block's student-row window

    const float* s_base = student + (size_t)g * NAUG * DIM;
    const float* t_base = teacher + (size_t)g * NORIG * DIM;
    const int*   k_base = kept + g * NAUG;

    const int ccol  = lane & 15;      // frag row select / score col within tile
    const int cquad = lane >> 4;      // 0..3, k-subchunk select

    const int hw = tid >> 5;          // 0..15 -> teacher tile row group
    const int hl = tid & 31;          // 16B slot within 512B row

    // ---- issue idx loads ----
    int idxv[16];
    #pragma unroll
    for (int it = 0; it < 16; ++it) idxv[it] = k_base[it * 16 + hw];

    // ---- issue student loads ----
    const int srow = rbase + wave * 16 + ccol;
    const float* rp = s_base + srow * DIM;
    float4 sv[8];
    #pragma unroll
    for (int kc = 0; kc < 4; ++kc) {
        sv[kc * 2]     = *reinterpret_cast<const float4*>(rp + kc * 32 + cquad * 8);
        sv[kc * 2 + 1] = *reinterpret_cast<const float4*>(rp + kc * 32 + cquad * 8 + 4);
    }

    // ---- issue ALL gather loads (two 8-row batches, both up-front) ----
    float4 gv0[8], gv1[8];
    #pragma unroll
    for (int i = 0; i < 8; ++i)
        gv0[i] = *reinterpret_cast<const float4*>(t_base + (size_t)idxv[i] * DIM + hl * 4);
    #pragma unroll
    for (int i = 0; i < 8; ++i)
        gv1[i] = *reinterpret_cast<const float4*>(t_base + (size_t)idxv[8 + i] * DIM + hl * 4);

    // ---- student: raw bf16 frags + sumsq (all gathers in flight) ----
    bf16x8 afrag[4];
    {
        float ss = 0.f;
        #pragma unroll
        for (int kc = 0; kc < 4; ++kc) {
            const float4 a = sv[kc * 2], b = sv[kc * 2 + 1];
            afrag[kc][0] = f32_to_bf16_bits(a.x); afrag[kc][1] = f32_to_bf16_bits(a.y);
            afrag[kc][2] = f32_to_bf16_bits(a.z); afrag[kc][3] = f32_to_bf16_bits(a.w);
            afrag[kc][4] = f32_to_bf16_bits(b.x); afrag[kc][5] = f32_to_bf16_bits(b.y);
            afrag[kc][6] = f32_to_bf16_bits(b.z); afrag[kc][7] = f32_to_bf16_bits(b.w);
            ss += a.x * a.x + a.y * a.y + a.z * a.z + a.w * a.w;
            ss += b.x * b.x + b.y * b.y + b.z * b.z + b.w * b.w;
        }
        ss += __shfl_xor(ss, 16);
        ss += __shfl_xor(ss, 32);
        if (cquad == 0)
            rs_lds[wave * 16 + ccol] = rsqrtf(fmaxf(ss, 1e-24f)) * INV_T;
    }

    char* tl = reinterpret_cast<char*>(t_lds);
    // ---- process gather batch 0 -> LDS rows 0..127 ----
    #pragma unroll
    for (int i = 0; i < 8; ++i) {
        const int j = i * 16 + hw;                 // 0..127
        const float4 v = gv0[i];
        short4 o;
        o.x = f32_to_bf16_bits(v.x); o.y = f32_to_bf16_bits(v.y);
        o.z = f32_to_bf16_bits(v.z); o.w = f32_to_bf16_bits(v.w);
        const int byte = j * 256 + ((hl * 8) ^ ((j & 7) << 4));
        *reinterpret_cast<short4*>(tl + byte) = o;
        float ss = v.x * v.x + v.y * v.y + v.z * v.z + v.w * v.w;
        ss += __shfl_xor(ss, 1);
        ss += __shfl_xor(ss, 2);
        ss += __shfl_xor(ss, 4);
        ss += __shfl_xor(ss, 8);
        ss += __shfl_xor(ss, 16);
        if (hl == 0) rt_lds[j] = rsqrtf(fmaxf(ss, 1e-24f));
    }
    __syncthreads();   // half 1 ready

    // ---- process gather batch 1 -> LDS rows 128..255 (writes land during MFMA h1) ----
    #pragma unroll
    for (int i = 0; i < 8; ++i) {
        const int j = (8 + i) * 16 + hw;           // 128..255
        const float4 v = gv1[i];
        short4 o;
        o.x = f32_to_bf16_bits(v.x); o.y = f32_to_bf16_bits(v.y);
        o.z = f32_to_bf16_bits(v.z); o.w = f32_to_bf16_bits(v.w);
        const int byte = j * 256 + ((hl * 8) ^ ((j & 7) << 4));
        *reinterpret_cast<short4*>(tl + byte) = o;
        float ss = v.x * v.x + v.y * v.y + v.z * v.z + v.w * v.w;
        ss += __shfl_xor(ss, 1);
        ss += __shfl_xor(ss, 2);
        ss += __shfl_xor(ss, 4);
        ss += __shfl_xor(ss, 8);
        ss += __shfl_xor(ss, 16);
        if (hl == 0) rt_lds[j] = rsqrtf(fmaxf(ss, 1e-24f));
    }

    // ---- MFMA + softmax-sum + diagonal, half 1 (cols 0..127) ----
    float sumexp[4] = {0.f, 0.f, 0.f, 0.f};
    float diagsum = 0.f;
    const char* tlc = reinterpret_cast<const char*>(t_lds);
    float rs[4];
    #pragma unroll
    for (int reg = 0; reg < 4; ++reg)
        rs[reg] = rs_lds[wave * 16 + cquad * 4 + reg];

    #pragma unroll 2
    for (int ct = 0; ct < 8; ++ct) {
        f32x4 acc = {0.f, 0.f, 0.f, 0.f};
        const int j = ct * 16 + ccol;
        const float rt = rt_lds[j];
        #pragma unroll
        for (int kc = 0; kc < 4; ++kc) {
            const int byte = j * 256 + (((kc * 64) + (cquad * 16)) ^ ((j & 7) << 4));
            const bf16x8 b = *reinterpret_cast<const bf16x8*>(tlc + byte);
            acc = __builtin_amdgcn_mfma_f32_16x16x32_bf16(afrag[kc], b, acc, 0, 0, 0);
        }
        #pragma unroll
        for (int reg = 0; reg < 4; ++reg) {
            const int row = rbase + wave * 16 + cquad * 4 + reg;
            const float l = acc[reg] * rs[reg] * rt;   // rs carries the *10
            sumexp[reg] += __expf(l);
            if (j == row) diagsum += l;
        }
    }
    __syncthreads();   // half 2 ready

    // ---- MFMA half 2 (cols 128..255) ----
    #pragma unroll 2
    for (int ct = 8; ct < 16; ++ct) {
        f32x4 acc = {0.f, 0.f, 0.f, 0.f};
        const int j = ct * 16 + ccol;
        const float rt = rt_lds[j];
        #pragma unroll
        for (int kc = 0; kc < 4; ++kc) {
            const int byte = j * 256 + (((kc * 64) + (cquad * 16)) ^ ((j & 7) << 4));
            const bf16x8 b = *reinterpret_cast<const bf16x8*>(tlc + byte);
            acc = __builtin_amdgcn_mfma_f32_16x16x32_bf16(afrag[kc], b, acc, 0, 0, 0);
        }
        #pragma unroll
        for (int reg = 0; reg < 4; ++reg) {
            const int row = rbase + wave * 16 + cquad * 4 + reg;
            const float l = acc[reg] * rs[reg] * rt;
            sumexp[reg] += __expf(l);
            if (j == row) diagsum += l;
        }
    }

    // ---- per-block reduce: sum_i log(sumexp_i) - sum_i diag_i ----
    float ce = 0.f;
    #pragma unroll
    for (int reg = 0; reg < 4; ++reg) {
        float s = sumexp[reg];
        s += __shfl_xor(s, 1);
        s += __shfl_xor(s, 2);
        s += __shfl_xor(s, 4);
        s += __shfl_xor(s, 8);
        if (ccol == 0) ce += __logf(s);
    }
    ce -= diagsum;
    ce += __shfl_xor(ce, 1);
    ce += __shfl_xor(ce, 2);
    ce += __shfl_xor(ce, 4);
    ce += __shfl_xor(ce, 8);
    ce += __shfl_xor(ce, 16);
    ce += __shfl_xor(ce, 32);

    if (lane == 0) red[wave] = ce;
    __syncthreads();
    if (tid == 0) {
        float t = 0.f;
        #pragma unroll
        for (int w = 0; w < 8; ++w) t += red[w];
        block_sums[bid] = t;
        __threadfence();                           // release partial
        const unsigned old = atomicAdd(counter, 1u);
        is_last = (old == NBLK - 1) ? 1 : 0;
    }
    __syncthreads();

    // ---- last block: deterministic final reduction (order fixed by tid) ----
    if (is_last) {
        __threadfence();
        // atomic read bypasses any stale cached copy (coherent-point access)
        float v = atomicAdd(&block_sums[tid], 0.0f);
        v += __shfl_xor(v, 1);
        v += __shfl_xor(v, 2);
        v += __shfl_xor(v, 4);
        v += __shfl_xor(v, 8);
        v += __shfl_xor(v, 16);
        v += __shfl_xor(v, 32);
        if (lane == 0) red[wave] = v;
        __syncthreads();
        if (tid == 0) {
            float t = 0.f;
            #pragma unroll
            for (int w = 0; w < 8; ++w) t += red[w];
            out[0] = t * (1.0f / ((float)G_NUM * (float)NAUG));
        }
    }
}

extern "C" void kernel_launch(void* const* d_in, const int* in_sizes, int n_in,
                              void* d_out, int out_size, void* d_ws, size_t ws_size,
                              hipStream_t stream) {
    (void)in_sizes; (void)n_in; (void)out_size; (void)ws_size;
    const float* student = (const float*)d_in[0];
    const float* teacher = (const float*)d_in[1];
    const int*   kept    = (const int*)d_in[2];

    unsigned* counter = (unsigned*)d_ws;                       // 4B
    float*    bs      = (float*)((char*)d_ws + 256);           // 512 floats
    float*    out     = (float*)d_out;

    hipMemsetAsync(counter, 0, sizeof(unsigned), stream);
    nlcl_main<<<NBLK, 512, 0, stream>>>(student, teacher, kept, bs, counter, out);
}

// Round 5
// 28.738 us; speedup vs baseline: 1.2917x; 1.2917x over previous
//
#include <hip/hip_runtime.h>
#include <hip/hip_bf16.h>

using f32x4  = __attribute__((ext_vector_type(4))) float;
using bf16x8 = __attribute__((ext_vector_type(8))) short;

constexpr int   G_NUM = 256;
constexpr int   NAUG  = 256;
constexpr int   NORIG = 512;
constexpr int   DIM   = 128;
constexpr float INV_T = 10.0f;
constexpr int   NBLK  = 512;

// round-to-nearest-even f32 -> bf16 bits
__device__ __forceinline__ short f32_to_bf16_bits(float x) {
    unsigned u = __float_as_uint(x);
    u += 0x7fffu + ((u >> 16) & 1u);
    return (short)(u >> 16);
}

// R2 structure (best: 24.45us) + fused deterministic final reduction.
// 512 blocks = 2 per graph (each owns 128 student rows). 512 threads = 8 waves.
// Teacher tile (256 gathered+normalized bf16 rows) in 64KB XOR-swizzled LDS.
// Tail: wrap-safe arrival counter (512 | 2^32 -> any start value works, no
// memset needed); last-arriving block re-reads the 512 partials through the
// coherence point and reduces in a FIXED order -> bitwise deterministic.
__global__ __launch_bounds__(512, 4) void nlcl_main(
    const float* __restrict__ student,
    const float* __restrict__ teacher,
    const int*   __restrict__ kept,
    float*       __restrict__ block_sums,
    unsigned*    __restrict__ counter,
    float*       __restrict__ out)
{
    __shared__ short t_lds[NAUG * DIM]; // [256 rows][128 bf16], swizzled, 64KB
    __shared__ float red[8];
    __shared__ int   is_last;

    const int bid = blockIdx.x;
    // XCD-bijective swizzle (512 = 8 XCDs x 64): logical pairs (2g,2g+1) same XCD
    const int logical = (bid & 7) * 64 + (bid >> 3);
    const int g    = logical >> 1;
    const int half = logical & 1;

    const int tid  = threadIdx.x;
    const int lane = tid & 63;
    const int wave = tid >> 6;        // 0..7
    const int rbase = half * 128;     // this block's student-row window

    const float* s_base = student + (size_t)g * NAUG * DIM;
    const float* t_base = teacher + (size_t)g * NORIG * DIM;
    const int*   k_base = kept + g * NAUG;

    const int ccol  = lane & 15;      // frag row select / score col within tile
    const int cquad = lane >> 4;      // 0..3, k-subchunk select

    // ---- hoist kept-index loads (head of longest dep chain) ----
    const int hw = tid >> 5;          // 0..15 (half-wave id)
    const int hl = tid & 31;
    int idxv[16];
    #pragma unroll
    for (int it = 0; it < 16; ++it) idxv[it] = k_base[it * 16 + hw];

    // ---- student -> normalized bf16 A-fragments ----
    // lane holds s[row = rbase + wave*16 + ccol][d = kc*32 + cquad*8 + 0..7]
    bf16x8 afrag[4];
    {
        const int row = rbase + wave * 16 + ccol;
        const float* rp = s_base + row * DIM;
        float sf[4][8];
        #pragma unroll
        for (int kc = 0; kc < 4; ++kc) {
            const int d0 = kc * 32 + cquad * 8;
            const float4 a = *reinterpret_cast<const float4*>(rp + d0);
            const float4 b = *reinterpret_cast<const float4*>(rp + d0 + 4);
            sf[kc][0] = a.x; sf[kc][1] = a.y; sf[kc][2] = a.z; sf[kc][3] = a.w;
            sf[kc][4] = b.x; sf[kc][5] = b.y; sf[kc][6] = b.z; sf[kc][7] = b.w;
        }
        float ss = 0.f;
        #pragma unroll
        for (int kc = 0; kc < 4; ++kc)
            #pragma unroll
            for (int e = 0; e < 8; ++e) ss += sf[kc][e] * sf[kc][e];
        ss += __shfl_xor(ss, 16);
        ss += __shfl_xor(ss, 32);
        const float scale = rsqrtf(fmaxf(ss, 1e-24f));
        #pragma unroll
        for (int kc = 0; kc < 4; ++kc)
            #pragma unroll
            for (int e = 0; e < 8; ++e)
                afrag[kc][e] = f32_to_bf16_bits(sf[kc][e] * scale);
    }

    // ---- teacher gather+normalize -> swizzled bf16 LDS ----
    // half-wave per row: 32 lanes x float4 = 512B row
    {
        char* tl = reinterpret_cast<char*>(t_lds);
        #pragma unroll
        for (int it = 0; it < 16; ++it) {
            const int j   = it * 16 + hw;          // 0..255
            const float* rp = t_base + (size_t)idxv[it] * DIM;
            const float4 v = *reinterpret_cast<const float4*>(rp + hl * 4);
            float ss = v.x * v.x + v.y * v.y + v.z * v.z + v.w * v.w;
            ss += __shfl_xor(ss, 1);
            ss += __shfl_xor(ss, 2);
            ss += __shfl_xor(ss, 4);
            ss += __shfl_xor(ss, 8);
            ss += __shfl_xor(ss, 16);
            const float scale = rsqrtf(fmaxf(ss, 1e-24f));
            short4 o;
            o.x = f32_to_bf16_bits(v.x * scale);
            o.y = f32_to_bf16_bits(v.y * scale);
            o.z = f32_to_bf16_bits(v.z * scale);
            o.w = f32_to_bf16_bits(v.w * scale);
            const int byte = j * 256 + ((hl * 8) ^ ((j & 7) << 4));
            *reinterpret_cast<short4*>(tl + byte) = o;
        }
    }
    __syncthreads();

    // ---- MFMA + softmax-sum + diagonal ----
    float sumexp[4] = {0.f, 0.f, 0.f, 0.f};
    float diagsum = 0.f;
    const char* tl = reinterpret_cast<const char*>(t_lds);

    for (int ct = 0; ct < 16; ++ct) {
        f32x4 acc = {0.f, 0.f, 0.f, 0.f};
        const int j = ct * 16 + ccol;             // teacher row = score col
        #pragma unroll
        for (int kc = 0; kc < 4; ++kc) {
            const int byte = j * 256 + (((kc * 64) + (cquad * 16)) ^ ((j & 7) << 4));
            const bf16x8 b = *reinterpret_cast<const bf16x8*>(tl + byte);
            acc = __builtin_amdgcn_mfma_f32_16x16x32_bf16(afrag[kc], b, acc, 0, 0, 0);
        }
        #pragma unroll
        for (int reg = 0; reg < 4; ++reg) {
            const int row = rbase + wave * 16 + cquad * 4 + reg;
            const float l = acc[reg] * INV_T;
            sumexp[reg] += __expf(l);
            if (j == row) diagsum += l;
        }
    }

    // ---- per-block: sum_i log(sumexp_i) - sum_i diag_i ----
    float ce = 0.f;
    #pragma unroll
    for (int reg = 0; reg < 4; ++reg) {
        float s = sumexp[reg];
        s += __shfl_xor(s, 1);
        s += __shfl_xor(s, 2);
        s += __shfl_xor(s, 4);
        s += __shfl_xor(s, 8);
        if (ccol == 0) ce += __logf(s);           // one lane per (cquad,reg) row
    }
    ce -= diagsum;
    ce += __shfl_xor(ce, 1);
    ce += __shfl_xor(ce, 2);
    ce += __shfl_xor(ce, 4);
    ce += __shfl_xor(ce, 8);
    ce += __shfl_xor(ce, 16);
    ce += __shfl_xor(ce, 32);

    if (lane == 0) red[wave] = ce;
    __syncthreads();
    if (tid == 0) {
        float t = 0.f;
        #pragma unroll
        for (int w = 0; w < 8; ++w) t += red[w];
        block_sums[bid] = t;
        __threadfence();                            // release partial
        const unsigned old = atomicAdd(counter, 1u);
        // 512 divides 2^32 -> exactly one block per call sees old%512==511,
        // regardless of the counter's starting value (no reset required).
        is_last = ((old & (NBLK - 1)) == (NBLK - 1)) ? 1 : 0;
    }
    __syncthreads();

    // ---- last-arriving block: deterministic fixed-order final reduction ----
    if (is_last) {
        __threadfence();                            // acquire
        // atomic read-modify-write with 0 bypasses stale cached copies
        float v = atomicAdd(&block_sums[tid], 0.0f);
        v += __shfl_xor(v, 1);
        v += __shfl_xor(v, 2);
        v += __shfl_xor(v, 4);
        v += __shfl_xor(v, 8);
        v += __shfl_xor(v, 16);
        v += __shfl_xor(v, 32);
        if (lane == 0) red[wave] = v;
        __syncthreads();
        if (tid == 0) {
            float t = 0.f;
            #pragma unroll
            for (int w = 0; w < 8; ++w) t += red[w];
            out[0] = t * (1.0f / ((float)G_NUM * (float)NAUG));
        }
    }
}

extern "C" void kernel_launch(void* const* d_in, const int* in_sizes, int n_in,
                              void* d_out, int out_size, void* d_ws, size_t ws_size,
                              hipStream_t stream) {
    (void)in_sizes; (void)n_in; (void)out_size; (void)ws_size;
    const float* student = (const float*)d_in[0];
    const float* teacher = (const float*)d_in[1];
    const int*   kept    = (const int*)d_in[2];

    unsigned* counter = (unsigned*)d_ws;                 // 4B (any value ok)
    float*    bs      = (float*)((char*)d_ws + 256);     // 512 floats
    float*    out     = (float*)d_out;

    nlcl_main<<<NBLK, 512, 0, stream>>>(student, teacher, kept, bs, counter, out);
}

// Round 6
// 23.156 us; speedup vs baseline: 1.6030x; 1.2411x over previous
//
#include <hip/hip_runtime.h>
#include <hip/hip_bf16.h>

using f32x4  = __attribute__((ext_vector_type(4))) float;
using bf16x8 = __attribute__((ext_vector_type(8))) short;

constexpr int   G_NUM = 256;
constexpr int   NAUG  = 256;
constexpr int   NORIG = 512;
constexpr int   DIM   = 128;
constexpr float INV_T = 10.0f;
constexpr int   NBLK  = 256;

// f32 stage: teacher rows DMA'd in pairs (1024B) with 16B pad per pair to
// break the 512B row-stride bank pattern on readback.
constexpr int PAIR_PITCH = 1040;                  // 1024 + 16
constexpr int STAGE_BYTES = 64 * PAIR_PITCH;      // 64 pairs = 128 rows = 66560B

// round-to-nearest-even f32 -> bf16 bits
__device__ __forceinline__ short f32_to_bf16_bits(float x) {
    unsigned u = __float_as_uint(x);
    u += 0x7fffu + ((u >> 16) & 1u);
    return (short)(u >> 16);
}

// 256 blocks = 1 per graph, 1 block/CU. 512 threads = 8 waves; wave owns 32
// student rows. Teacher gathered via global_load_lds (async DMA, no VGPR
// round-trip) into a 65KB f32 stage (half tile = 128 rows at a time), then
// normalized+converted into a 64KB XOR-swizzled bf16 tile. MFMA on half 1
// overlaps half-2 DMA.
__global__ __launch_bounds__(512, 2) void nlcl_main(
    const float* __restrict__ student,
    const float* __restrict__ teacher,
    const int*   __restrict__ kept,
    float*       __restrict__ block_sums)
{
    __shared__ __align__(16) char  stage[STAGE_BYTES];   // f32 half-tile stage
    __shared__ __align__(16) short tile[NAUG * DIM];     // bf16 tile, swizzled, 64KB
    __shared__ float red[8];

    const int g    = blockIdx.x;
    const int tid  = threadIdx.x;
    const int lane = tid & 63;
    const int wave = tid >> 6;        // 0..7

    const float* s_base = student + (size_t)g * NAUG * DIM;
    const float* t_base = teacher + (size_t)g * NORIG * DIM;
    const int*   k_base = kept + g * NAUG;

    const int ccol  = lane & 15;      // frag row select / score col in tile
    const int cquad = lane >> 4;      // 0..3

    // ---- issue idx loads: srcv[t] = kept row for pair (h= t>>3, i= t&7) ----
    // pair p = h*64 + wave*8 + i; this lane covers row p*2 + (lane>>5)
    int srcv[16];
    #pragma unroll
    for (int t = 0; t < 16; ++t) {
        const int pair = (t >> 3) * 64 + wave * 8 + (t & 7);
        srcv[t] = k_base[pair * 2 + (lane >> 5)];
    }

    // ---- issue student loads (both 16-row groups) ----
    float4 sv[16];
    #pragma unroll
    for (int rt = 0; rt < 2; ++rt) {
        const float* rp = s_base + (wave * 32 + rt * 16 + ccol) * DIM;
        #pragma unroll
        for (int kc = 0; kc < 4; ++kc) {
            sv[rt * 8 + kc * 2]     = *reinterpret_cast<const float4*>(rp + kc * 32 + cquad * 8);
            sv[rt * 8 + kc * 2 + 1] = *reinterpret_cast<const float4*>(rp + kc * 32 + cquad * 8 + 4);
        }
    }

    // ---- issue teacher half-1 DMA: rows 0..127 -> stage (fire-and-forget) ----
    // one instr = 64 lanes x 16B = 2 rows (lane>>5 selects row in pair)
    #pragma unroll
    for (int i = 0; i < 8; ++i) {
        const float* src = t_base + (size_t)srcv[i] * DIM + (lane & 31) * 4;
        char* dst = stage + (wave * 8 + i) * PAIR_PITCH;
        __builtin_amdgcn_global_load_lds(
            (const __attribute__((address_space(1))) void*)src,
            (__attribute__((address_space(3))) void*)dst, 16, 0, 0);
    }

    // ---- student: normalize -> bf16 A-frags (overlaps teacher DMA) ----
    bf16x8 afrag[2][4];
    #pragma unroll
    for (int rt = 0; rt < 2; ++rt) {
        float ss = 0.f;
        #pragma unroll
        for (int q = 0; q < 8; ++q) {
            const float4 v = sv[rt * 8 + q];
            ss += v.x * v.x + v.y * v.y + v.z * v.z + v.w * v.w;
        }
        ss += __shfl_xor(ss, 16);
        ss += __shfl_xor(ss, 32);
        const float scale = rsqrtf(fmaxf(ss, 1e-24f));
        #pragma unroll
        for (int kc = 0; kc < 4; ++kc) {
            const float4 a = sv[rt * 8 + kc * 2], b = sv[rt * 8 + kc * 2 + 1];
            afrag[rt][kc][0] = f32_to_bf16_bits(a.x * scale);
            afrag[rt][kc][1] = f32_to_bf16_bits(a.y * scale);
            afrag[rt][kc][2] = f32_to_bf16_bits(a.z * scale);
            afrag[rt][kc][3] = f32_to_bf16_bits(a.w * scale);
            afrag[rt][kc][4] = f32_to_bf16_bits(b.x * scale);
            afrag[rt][kc][5] = f32_to_bf16_bits(b.y * scale);
            afrag[rt][kc][6] = f32_to_bf16_bits(b.z * scale);
            afrag[rt][kc][7] = f32_to_bf16_bits(b.w * scale);
        }
    }

    __syncthreads();   // B1: half-1 DMA complete (vmcnt0 before barrier)

    // ---- convert half-1: stage f32 -> normalized bf16 tile rows 0..127 ----
    char* tb = reinterpret_cast<char*>(tile);
    {
        const int row_l = tid >> 2;          // 0..127
        const int sub   = tid & 3;           // 32-float chunk of the row
        const int j     = row_l;             // tile row
        const char* sp = stage + (row_l >> 1) * PAIR_PITCH + (row_l & 1) * 512 + sub * 128;
        float vals[32]; float ss = 0.f;
        #pragma unroll
        for (int it = 0; it < 8; ++it) {
            const float4 v = *reinterpret_cast<const float4*>(sp + it * 16);
            vals[it * 4] = v.x; vals[it * 4 + 1] = v.y;
            vals[it * 4 + 2] = v.z; vals[it * 4 + 3] = v.w;
            ss += v.x * v.x + v.y * v.y + v.z * v.z + v.w * v.w;
        }
        ss += __shfl_xor(ss, 1);
        ss += __shfl_xor(ss, 2);
        const float scale = rsqrtf(fmaxf(ss, 1e-24f));
        #pragma unroll
        for (int p = 0; p < 4; ++p) {
            bf16x8 o;
            #pragma unroll
            for (int e = 0; e < 8; ++e) o[e] = f32_to_bf16_bits(vals[p * 8 + e] * scale);
            const int byte = j * 256 + ((sub * 64 + p * 16) ^ ((j & 7) << 4));
            *reinterpret_cast<bf16x8*>(tb + byte) = o;
        }
    }
    __syncthreads();   // B2: stage free, tile half-1 ready

    // ---- issue teacher half-2 DMA (rows 128..255) ----
    #pragma unroll
    for (int i = 0; i < 8; ++i) {
        const float* src = t_base + (size_t)srcv[8 + i] * DIM + (lane & 31) * 4;
        char* dst = stage + (wave * 8 + i) * PAIR_PITCH;
        __builtin_amdgcn_global_load_lds(
            (const __attribute__((address_space(1))) void*)src,
            (__attribute__((address_space(3))) void*)dst, 16, 0, 0);
    }

    // ---- MFMA + softmax-sum + diagonal, cols 0..127 (overlaps half-2 DMA) ----
    float sumexp[2][4] = {{0.f,0.f,0.f,0.f},{0.f,0.f,0.f,0.f}};
    float diagsum = 0.f;
    const char* tlc = reinterpret_cast<const char*>(tile);

    #pragma unroll 2
    for (int ct = 0; ct < 8; ++ct) {
        f32x4 acc0 = {0.f,0.f,0.f,0.f};
        f32x4 acc1 = {0.f,0.f,0.f,0.f};
        const int j = ct * 16 + ccol;
        #pragma unroll
        for (int kc = 0; kc < 4; ++kc) {
            const int byte = j * 256 + (((kc * 64) + (cquad * 16)) ^ ((j & 7) << 4));
            const bf16x8 b = *reinterpret_cast<const bf16x8*>(tlc + byte);
            acc0 = __builtin_amdgcn_mfma_f32_16x16x32_bf16(afrag[0][kc], b, acc0, 0, 0, 0);
            acc1 = __builtin_amdgcn_mfma_f32_16x16x32_bf16(afrag[1][kc], b, acc1, 0, 0, 0);
        }
        #pragma unroll
        for (int reg = 0; reg < 4; ++reg) {
            const int row0 = wave * 32 + cquad * 4 + reg;
            const int row1 = row0 + 16;
            const float l0 = acc0[reg] * INV_T;
            const float l1 = acc1[reg] * INV_T;
            sumexp[0][reg] += __expf(l0);
            sumexp[1][reg] += __expf(l1);
            if (j == row0) diagsum += l0;
            if (j == row1) diagsum += l1;
        }
    }
    __syncthreads();   // B3: half-2 DMA complete

    // ---- convert half-2 -> tile rows 128..255 ----
    {
        const int row_l = tid >> 2;
        const int sub   = tid & 3;
        const int j     = 128 + row_l;
        const char* sp = stage + (row_l >> 1) * PAIR_PITCH + (row_l & 1) * 512 + sub * 128;
        float vals[32]; float ss = 0.f;
        #pragma unroll
        for (int it = 0; it < 8; ++it) {
            const float4 v = *reinterpret_cast<const float4*>(sp + it * 16);
            vals[it * 4] = v.x; vals[it * 4 + 1] = v.y;
            vals[it * 4 + 2] = v.z; vals[it * 4 + 3] = v.w;
            ss += v.x * v.x + v.y * v.y + v.z * v.z + v.w * v.w;
        }
        ss += __shfl_xor(ss, 1);
        ss += __shfl_xor(ss, 2);
        const float scale = rsqrtf(fmaxf(ss, 1e-24f));
        #pragma unroll
        for (int p = 0; p < 4; ++p) {
            bf16x8 o;
            #pragma unroll
            for (int e = 0; e < 8; ++e) o[e] = f32_to_bf16_bits(vals[p * 8 + e] * scale);
            const int byte = j * 256 + ((sub * 64 + p * 16) ^ ((j & 7) << 4));
            *reinterpret_cast<bf16x8*>(tb + byte) = o;
        }
    }
    __syncthreads();   // B4: tile half-2 ready

    // ---- MFMA cols 128..255 ----
    #pragma unroll 2
    for (int ct = 8; ct < 16; ++ct) {
        f32x4 acc0 = {0.f,0.f,0.f,0.f};
        f32x4 acc1 = {0.f,0.f,0.f,0.f};
        const int j = ct * 16 + ccol;
        #pragma unroll
        for (int kc = 0; kc < 4; ++kc) {
            const int byte = j * 256 + (((kc * 64) + (cquad * 16)) ^ ((j & 7) << 4));
            const bf16x8 b = *reinterpret_cast<const bf16x8*>(tlc + byte);
            acc0 = __builtin_amdgcn_mfma_f32_16x16x32_bf16(afrag[0][kc], b, acc0, 0, 0, 0);
            acc1 = __builtin_amdgcn_mfma_f32_16x16x32_bf16(afrag[1][kc], b, acc1, 0, 0, 0);
        }
        #pragma unroll
        for (int reg = 0; reg < 4; ++reg) {
            const int row0 = wave * 32 + cquad * 4 + reg;
            const int row1 = row0 + 16;
            const float l0 = acc0[reg] * INV_T;
            const float l1 = acc1[reg] * INV_T;
            sumexp[0][reg] += __expf(l0);
            sumexp[1][reg] += __expf(l1);
            if (j == row0) diagsum += l0;
            if (j == row1) diagsum += l1;
        }
    }

    // ---- per-block: sum_i log(sumexp_i) - sum_i diag_i ----
    float ce = 0.f;
    #pragma unroll
    for (int rt = 0; rt < 2; ++rt) {
        #pragma unroll
        for (int reg = 0; reg < 4; ++reg) {
            float s = sumexp[rt][reg];
            s += __shfl_xor(s, 1);
            s += __shfl_xor(s, 2);
            s += __shfl_xor(s, 4);
            s += __shfl_xor(s, 8);
            if (ccol == 0) ce += __logf(s);
        }
    }
    ce -= diagsum;
    ce += __shfl_xor(ce, 1);
    ce += __shfl_xor(ce, 2);
    ce += __shfl_xor(ce, 4);
    ce += __shfl_xor(ce, 8);
    ce += __shfl_xor(ce, 16);
    ce += __shfl_xor(ce, 32);

    if (lane == 0) red[wave] = ce;
    __syncthreads();
    if (tid == 0) {
        float t = 0.f;
        #pragma unroll
        for (int w = 0; w < 8; ++w) t += red[w];
        block_sums[g] = t;
    }
}

// Deterministic final reduction over 256 graph partials; out = sum / (G*NA)
__global__ void nlcl_reduce(const float* __restrict__ block_sums,
                            float* __restrict__ out)
{
    __shared__ float r[4];
    const int tid = threadIdx.x;   // 256 threads
    float v = block_sums[tid];
    v += __shfl_xor(v, 1);
    v += __shfl_xor(v, 2);
    v += __shfl_xor(v, 4);
    v += __shfl_xor(v, 8);
    v += __shfl_xor(v, 16);
    v += __shfl_xor(v, 32);
    if ((tid & 63) == 0) r[tid >> 6] = v;
    __syncthreads();
    if (tid == 0)
        out[0] = (r[0] + r[1] + r[2] + r[3]) * (1.0f / ((float)G_NUM * (float)NAUG));
}

extern "C" void kernel_launch(void* const* d_in, const int* in_sizes, int n_in,
                              void* d_out, int out_size, void* d_ws, size_t ws_size,
                              hipStream_t stream) {
    (void)in_sizes; (void)n_in; (void)out_size; (void)ws_size;
    const float* student = (const float*)d_in[0];
    const float* teacher = (const float*)d_in[1];
    const int*   kept    = (const int*)d_in[2];
    float* bs  = (float*)d_ws;
    float* out = (float*)d_out;

    nlcl_main<<<NBLK, 512, 0, stream>>>(student, teacher, kept, bs);
    nlcl_reduce<<<1, 256, 0, stream>>>(bs, out);
}

// Round 8
// 22.615 us; speedup vs baseline: 1.6413x; 1.0239x over previous
//
#include <hip/hip_runtime.h>
#include <hip/hip_bf16.h>

using f32x4  = __attribute__((ext_vector_type(4))) float;
using bf16x8 = __attribute__((ext_vector_type(8))) short;

constexpr int   G_NUM = 256;
constexpr int   NAUG  = 256;
constexpr int   NORIG = 512;
constexpr int   DIM   = 128;
constexpr float INV_T = 10.0f;
constexpr int   NBLK  = 256;

// f32 stage: teacher rows DMA'd in pairs (1024B) with 16B pad per pair.
// Quarter tile = 64 rows = 32 pairs per slot; two slots double-buffered.
constexpr int PAIR_PITCH = 1040;                  // 1024 + 16
constexpr int SLOT_BYTES = 32 * PAIR_PITCH;       // 33280
constexpr int STAGE_BYTES = 2 * SLOT_BYTES;       // 66560

// round-to-nearest-even f32 -> bf16 bits
__device__ __forceinline__ short f32_to_bf16_bits(float x) {
    unsigned u = __float_as_uint(x);
    u += 0x7fffu + ((u >> 16) & 1u);
    return (short)(u >> 16);
}

// 256 blocks = 1 per graph, 1 block/CU. 512 threads = 8 waves.
// R6 body (proven 23.16us) deepened: teacher gathered via global_load_lds in
// FOUR 64-row quarters, double-buffered f32 stage, counted s_waitcnt vmcnt(4)
// + raw s_barrier (no full drain) so convert+MFMA of quarter k overlap the
// DMA of quarters k+1/k+2. Only Q0's 16KB drain is exposed.
__global__ __launch_bounds__(512, 2) void nlcl_main(
    const float* __restrict__ student,
    const float* __restrict__ teacher,
    const int*   __restrict__ kept,
    float*       __restrict__ block_sums)
{
    __shared__ __align__(16) char  stage[STAGE_BYTES];   // 2 slots, f32 quarters
    __shared__ __align__(16) short tile[NAUG * DIM];     // bf16 tile, swizzled, 64KB
    __shared__ float red[8];

    const int g    = blockIdx.x;
    const int tid  = threadIdx.x;
    const int lane = tid & 63;
    const int wave = tid >> 6;        // 0..7

    const float* s_base = student + (size_t)g * NAUG * DIM;
    const float* t_base = teacher + (size_t)g * NORIG * DIM;
    const int*   k_base = kept + g * NAUG;

    const int ccol  = lane & 15;      // frag row select / score col in tile
    const int cquad = lane >> 4;      // 0..3

    // ---- issue idx loads: quarter k, instr i covers pair k*32+wave*4+i ----
    // this lane's row within the pair = lane>>5
    int srcv[16];
    #pragma unroll
    for (int t = 0; t < 16; ++t) {
        const int pair = (t >> 2) * 32 + wave * 4 + (t & 3);
        srcv[t] = k_base[pair * 2 + (lane >> 5)];
    }

    // ---- issue student loads ----
    float4 sv[16];
    #pragma unroll
    for (int rt = 0; rt < 2; ++rt) {
        const float* rp = s_base + (wave * 32 + rt * 16 + ccol) * DIM;
        #pragma unroll
        for (int kc = 0; kc < 4; ++kc) {
            sv[rt * 8 + kc * 2]     = *reinterpret_cast<const float4*>(rp + kc * 32 + cquad * 8);
            sv[rt * 8 + kc * 2 + 1] = *reinterpret_cast<const float4*>(rp + kc * 32 + cquad * 8 + 4);
        }
    }

    // one DMA instr = 64 lanes x 16B = one row pair (lane>>5 = row in pair)
    auto dma_quarter = [&](int k) {
        #pragma unroll
        for (int i = 0; i < 4; ++i) {
            const float* src = t_base + (size_t)srcv[k * 4 + i] * DIM + (lane & 31) * 4;
            char* dst = stage + (k & 1) * SLOT_BYTES + (wave * 4 + i) * PAIR_PITCH;
            __builtin_amdgcn_global_load_lds(
                (const __attribute__((address_space(1))) void*)src,
                (__attribute__((address_space(3))) void*)dst, 16, 0, 0);
        }
    };

    // stage f32 quarter -> normalized bf16 tile rows 64k..64k+63
    // 8 threads per row; each handles 16 floats.
    auto convert_quarter = [&](int k) {
        const int row_l = tid >> 3;          // 0..63
        const int sub   = tid & 7;           // 16-float chunk
        const int j     = k * 64 + row_l;    // tile row
        const char* sp = stage + (k & 1) * SLOT_BYTES
                       + (row_l >> 1) * PAIR_PITCH + (row_l & 1) * 512 + sub * 64;
        float vals[16]; float ss = 0.f;
        #pragma unroll
        for (int it = 0; it < 4; ++it) {
            const float4 v = *reinterpret_cast<const float4*>(sp + it * 16);
            vals[it * 4] = v.x; vals[it * 4 + 1] = v.y;
            vals[it * 4 + 2] = v.z; vals[it * 4 + 3] = v.w;
            ss += v.x * v.x + v.y * v.y + v.z * v.z + v.w * v.w;
        }
        ss += __shfl_xor(ss, 1);
        ss += __shfl_xor(ss, 2);
        ss += __shfl_xor(ss, 4);
        const float scale = rsqrtf(fmaxf(ss, 1e-24f));
        char* tb = reinterpret_cast<char*>(tile);
        #pragma unroll
        for (int p = 0; p < 2; ++p) {
            bf16x8 o;
            #pragma unroll
            for (int e = 0; e < 8; ++e) o[e] = f32_to_bf16_bits(vals[p * 8 + e] * scale);
            const int byte = j * 256 + ((sub * 32 + p * 16) ^ ((j & 7) << 4));
            *reinterpret_cast<bf16x8*>(tb + byte) = o;
        }
    };

    // ---- issue quarters 0,1 DMA (fire-and-forget) ----
    dma_quarter(0);
    dma_quarter(1);

    // ---- student: normalize -> bf16 A-frags (overlaps DMA) ----
    bf16x8 afrag[2][4];
    #pragma unroll
    for (int rt = 0; rt < 2; ++rt) {
        float ss = 0.f;
        #pragma unroll
        for (int q = 0; q < 8; ++q) {
            const float4 v = sv[rt * 8 + q];
            ss += v.x * v.x + v.y * v.y + v.z * v.z + v.w * v.w;
        }
        ss += __shfl_xor(ss, 16);
        ss += __shfl_xor(ss, 32);
        const float scale = rsqrtf(fmaxf(ss, 1e-24f));
        #pragma unroll
        for (int kc = 0; kc < 4; ++kc) {
            const float4 a = sv[rt * 8 + kc * 2], b = sv[rt * 8 + kc * 2 + 1];
            afrag[rt][kc][0] = f32_to_bf16_bits(a.x * scale);
            afrag[rt][kc][1] = f32_to_bf16_bits(a.y * scale);
            afrag[rt][kc][2] = f32_to_bf16_bits(a.z * scale);
            afrag[rt][kc][3] = f32_to_bf16_bits(a.w * scale);
            afrag[rt][kc][4] = f32_to_bf16_bits(b.x * scale);
            afrag[rt][kc][5] = f32_to_bf16_bits(b.y * scale);
            afrag[rt][kc][6] = f32_to_bf16_bits(b.z * scale);
            afrag[rt][kc][7] = f32_to_bf16_bits(b.w * scale);
        }
    }

    float sumexp[2][4] = {{0.f,0.f,0.f,0.f},{0.f,0.f,0.f,0.f}};
    float diagsum = 0.f;
    const char* tlc = reinterpret_cast<const char*>(tile);

    // MFMA col-tiles 4k..4k+3 (tile rows 64k..64k+63)
    auto mfma_quarter = [&](int k) {
        #pragma unroll
        for (int ct = 4 * k; ct < 4 * k + 4; ++ct) {
            f32x4 acc0 = {0.f,0.f,0.f,0.f};
            f32x4 acc1 = {0.f,0.f,0.f,0.f};
            const int j = ct * 16 + ccol;
            #pragma unroll
            for (int kc = 0; kc < 4; ++kc) {
                const int byte = j * 256 + (((kc * 64) + (cquad * 16)) ^ ((j & 7) << 4));
                const bf16x8 b = *reinterpret_cast<const bf16x8*>(tlc + byte);
                acc0 = __builtin_amdgcn_mfma_f32_16x16x32_bf16(afrag[0][kc], b, acc0, 0, 0, 0);
                acc1 = __builtin_amdgcn_mfma_f32_16x16x32_bf16(afrag[1][kc], b, acc1, 0, 0, 0);
            }
            #pragma unroll
            for (int reg = 0; reg < 4; ++reg) {
                const int row0 = wave * 32 + cquad * 4 + reg;
                const int row1 = row0 + 16;
                const float l0 = acc0[reg] * INV_T;
                const float l1 = acc1[reg] * INV_T;
                sumexp[0][reg] += __expf(l0);
                sumexp[1][reg] += __expf(l1);
                if (j == row0) diagsum += l0;
                if (j == row1) diagsum += l1;
            }
        }
    };

    // ---- quarter pipeline ----
    // k=0: wait Q0 (Q1's 4 newer ops keep Q0 out of the newest-4)
    asm volatile("s_waitcnt vmcnt(4)" ::: "memory");
    __builtin_amdgcn_s_barrier();
    convert_quarter(0);
    asm volatile("s_waitcnt lgkmcnt(0)" ::: "memory");
    __builtin_amdgcn_s_barrier();
    dma_quarter(2);                   // slot0 free (all waves past convert 0)
    mfma_quarter(0);                  // overlaps Q2 DMA

    // k=1
    asm volatile("s_waitcnt vmcnt(4)" ::: "memory");
    __builtin_amdgcn_s_barrier();
    convert_quarter(1);
    asm volatile("s_waitcnt lgkmcnt(0)" ::: "memory");
    __builtin_amdgcn_s_barrier();
    dma_quarter(3);                   // slot1 free
    mfma_quarter(1);                  // overlaps Q3 DMA

    // k=2
    asm volatile("s_waitcnt vmcnt(4)" ::: "memory");
    __builtin_amdgcn_s_barrier();
    convert_quarter(2);
    asm volatile("s_waitcnt lgkmcnt(0)" ::: "memory");
    __builtin_amdgcn_s_barrier();
    mfma_quarter(2);

    // k=3: last quarter -> full drain
    asm volatile("s_waitcnt vmcnt(0)" ::: "memory");
    __builtin_amdgcn_s_barrier();
    convert_quarter(3);
    asm volatile("s_waitcnt lgkmcnt(0)" ::: "memory");
    __builtin_amdgcn_s_barrier();
    mfma_quarter(3);

    // ---- per-block: sum_i log(sumexp_i) - sum_i diag_i ----
    float ce = 0.f;
    #pragma unroll
    for (int rt = 0; rt < 2; ++rt) {
        #pragma unroll
        for (int reg = 0; reg < 4; ++reg) {
            float s = sumexp[rt][reg];
            s += __shfl_xor(s, 1);
            s += __shfl_xor(s, 2);
            s += __shfl_xor(s, 4);
            s += __shfl_xor(s, 8);
            if (ccol == 0) ce += __logf(s);
        }
    }
    ce -= diagsum;
    ce += __shfl_xor(ce, 1);
    ce += __shfl_xor(ce, 2);
    ce += __shfl_xor(ce, 4);
    ce += __shfl_xor(ce, 8);
    ce += __shfl_xor(ce, 16);
    ce += __shfl_xor(ce, 32);

    if (lane == 0) red[wave] = ce;
    __syncthreads();
    if (tid == 0) {
        float t = 0.f;
        #pragma unroll
        for (int w = 0; w < 8; ++w) t += red[w];
        block_sums[g] = t;
    }
}

// Deterministic final reduction over 256 graph partials; out = sum / (G*NA)
__global__ void nlcl_reduce(const float* __restrict__ block_sums,
                            float* __restrict__ out)
{
    __shared__ float r[4];
    const int tid = threadIdx.x;   // 256 threads
    float v = block_sums[tid];
    v += __shfl_xor(v, 1);
    v += __shfl_xor(v, 2);
    v += __shfl_xor(v, 4);
    v += __shfl_xor(v, 8);
    v += __shfl_xor(v, 16);
    v += __shfl_xor(v, 32);
    if ((tid & 63) == 0) r[tid >> 6] = v;
    __syncthreads();
    if (tid == 0)
        out[0] = (r[0] + r[1] + r[2] + r[3]) * (1.0f / ((float)G_NUM * (float)NAUG));
}

extern "C" void kernel_launch(void* const* d_in, const int* in_sizes, int n_in,
                              void* d_out, int out_size, void* d_ws, size_t ws_size,
                              hipStream_t stream) {
    (void)in_sizes; (void)n_in; (void)out_size; (void)ws_size;
    const float* student = (const float*)d_in[0];
    const float* teacher = (const float*)d_in[1];
    const int*   kept    = (const int*)d_in[2];
    float* bs  = (float*)d_ws;
    float* out = (float*)d_out;

    nlcl_main<<<NBLK, 512, 0, stream>>>(student, teacher, kept, bs);
    nlcl_reduce<<<1, 256, 0, stream>>>(bs, out);
}